// Round 1
// baseline (3567.614 us; speedup 1.0000x reference)
//
#include <hip/hip_runtime.h>
#include <hip/hip_bf16.h>
#include <math.h>

#define B_SZ 2048
#define DIN 1024
#define DENC 4096
#define T_ITERS 30

typedef __attribute__((ext_vector_type(8))) short short8;
typedef __attribute__((ext_vector_type(4))) float f32x4;

typedef __attribute__((address_space(3))) void lds_void;
typedef const __attribute__((address_space(1))) void glb_void;

__device__ inline short f2bf(float f) {
  union { float f; unsigned u; } v; v.f = f;
  unsigned r = v.u + 0x7fffu + ((v.u >> 16) & 1u);
  return (short)(r >> 16);
}

__device__ inline void gload_lds16(const void* g, void* l) {
  __builtin_amdgcn_global_load_lds((glb_void*)g, (lds_void*)l, 16, 0, 0);
}

// C[M,N] = A[M,K] * B[N,K]^T  (both operands K-contiguous, bf16 bits in short)
// MODE 0: out_bf = bf16(X - acc)          (residual r, bf16)
// MODE 1: FISTA update epilogue           (yk/x_old f32 state, writes yk_bf16)
// MODE 2: out f32 = acc                   (final z)
template<int BN, int K, int MODE>
__global__ __launch_bounds__(256)
void gemm_bt(const short* __restrict__ A, const short* __restrict__ Bm,
             const float* __restrict__ X,   // MODE 0: x input
             float* __restrict__ O0,        // MODE 1: yk_f32; MODE 2: z out
             float* __restrict__ O1,        // MODE 1: x_old (aliases d_out x_new)
             short* __restrict__ OB,        // MODE 0: r_bf16; MODE 1: yk_bf16
             float cmom, int last, int Nld)
{
  constexpr int BM = 128;
  constexpr int WN = BN / 2;   // wave tile n (waves laid out 2x2)
  constexpr int FM = 4;        // 64/16 m-fragments per wave
  constexpr int FN = WN / 16;  // n-fragments per wave
  constexpr int KSTEPS = K / 32;

  __shared__ short As[BM * 32];
  __shared__ short Bs[BN * 32];

  const int tid  = threadIdx.x;
  const int lane = tid & 63;
  const int w    = tid >> 6;
  const int wm   = w >> 1, wn = w & 1;
  const long a_row0 = (long)blockIdx.y * BM;
  const long b_row0 = (long)blockIdx.x * BN;

  f32x4 acc[FM][FN];
#pragma unroll
  for (int i = 0; i < FM; ++i)
#pragma unroll
    for (int j = 0; j < FN; ++j) acc[i][j] = (f32x4){0.f, 0.f, 0.f, 0.f};

  for (int kt = 0; kt < KSTEPS; ++kt) {
    const int k0 = kt * 32;
    __syncthreads();
    // stage A tile [BM][32] bf16, linear LDS image = idx16*16 bytes
#pragma unroll
    for (int rr = 0; rr < BM / 64; ++rr) {
      int idx16 = rr * 256 + tid;
      int row = idx16 >> 2, ce = (idx16 & 3) * 8;
      gload_lds16(A + (a_row0 + row) * K + k0 + ce,
                  As + (rr * 256 + (tid & 192)) * 8);
    }
#pragma unroll
    for (int rr = 0; rr < BN / 64; ++rr) {
      int idx16 = rr * 256 + tid;
      int row = idx16 >> 2, ce = (idx16 & 3) * 8;
      gload_lds16(Bm + (b_row0 + row) * K + k0 + ce,
                  Bs + (rr * 256 + (tid & 192)) * 8);
    }
    asm volatile("s_waitcnt vmcnt(0)" ::: "memory");
    __syncthreads();

    short8 af[FM], bfr[FN];
#pragma unroll
    for (int i = 0; i < FM; ++i) {
      int row = wm * 64 + i * 16 + (lane & 15);
      af[i] = *(const short8*)(As + row * 32 + (lane >> 4) * 8);
    }
#pragma unroll
    for (int j = 0; j < FN; ++j) {
      int row = wn * WN + j * 16 + (lane & 15);
      bfr[j] = *(const short8*)(Bs + row * 32 + (lane >> 4) * 8);
    }
#pragma unroll
    for (int i = 0; i < FM; ++i)
#pragma unroll
      for (int j = 0; j < FN; ++j)
        acc[i][j] = __builtin_amdgcn_mfma_f32_16x16x32_bf16(af[i], bfr[j], acc[i][j], 0, 0, 0);
  }

  // epilogue: C/D layout col=lane&15, row=(lane>>4)*4+reg
  const int rbase = wm * 64 + ((lane >> 4) << 2);
  const int cbase = wn * WN + (lane & 15);
#pragma unroll
  for (int i = 0; i < FM; ++i) {
#pragma unroll
    for (int j = 0; j < FN; ++j) {
#pragma unroll
      for (int r = 0; r < 4; ++r) {
        long row = a_row0 + rbase + i * 16 + r;
        long col = b_row0 + cbase + j * 16;
        long idx = row * (long)Nld + col;
        float v = acc[i][j][r];
        if (MODE == 0) {
          OB[idx] = f2bf(X[idx] - v);
        } else if (MODE == 2) {
          O0[idx] = v;
        } else {
          float ykv = O0[idx];
          float xg  = ykv + v * 0.1f;               // yk + H^T r / L
          float s   = fabsf(xg) - 0.01f;            // lam / L
          float xn  = s > 0.f ? copysignf(s, xg) : 0.f;
          float xo  = O1[idx];
          float yn  = xn + cmom * (xn - xo);        // momentum (cmom==0 at iter 0)
          O1[idx] = xn;                             // x_old <- x_new (also final output)
          O0[idx] = yn;                             // yk f32
          OB[idx] = f2bf(last ? xn : yn);           // operand for next GEMM1 / final z
        }
      }
    }
  }
}

// pack H (f32 [DIN,DENC]) -> Hbf [DIN,DENC] bf16 and Htbf [DENC,DIN] bf16
__global__ void pack_H_kernel(const float* __restrict__ H, short* __restrict__ Hbf,
                              short* __restrict__ Htbf) {
  __shared__ float tile[32][33];
  int tx = threadIdx.x, ty0 = threadIdx.y;
  int j0 = blockIdx.x * 32;  // DENC
  int i0 = blockIdx.y * 32;  // DIN
#pragma unroll
  for (int r = 0; r < 4; ++r) {
    int ty = ty0 * 4 + r;
    float v = H[(long)(i0 + ty) * DENC + j0 + tx];
    tile[ty][tx] = v;
    Hbf[(long)(i0 + ty) * DENC + j0 + tx] = f2bf(v);
  }
  __syncthreads();
#pragma unroll
  for (int r = 0; r < 4; ++r) {
    int ty = ty0 * 4 + r;
    Htbf[(long)(j0 + ty) * DIN + i0 + tx] = f2bf(tile[tx][ty]);
  }
}

extern "C" void kernel_launch(void* const* d_in, const int* in_sizes, int n_in,
                              void* d_out, int out_size, void* d_ws, size_t ws_size,
                              hipStream_t stream) {
  const float* x = (const float*)d_in[0];  // [2048,1024]
  const float* H = (const float*)d_in[1];  // [1024,4096]

  float* z_out = (float*)d_out;                       // [2048,1024]
  float* xold  = (float*)d_out + (size_t)B_SZ * DIN;  // [2048,4096] doubles as x_old

  char* ws = (char*)d_ws;
  size_t off = 0;
  float* yk   = (float*)(ws + off); off += (size_t)B_SZ * DENC * 4;  // 32 MB
  short* ykbf = (short*)(ws + off); off += (size_t)B_SZ * DENC * 2;  // 16 MB
  short* rbf  = (short*)(ws + off); off += (size_t)B_SZ * DIN  * 2;  //  4 MB
  short* Hbf  = (short*)(ws + off); off += (size_t)DIN  * DENC * 2;  //  8 MB
  short* Htbf = (short*)(ws + off);                                  //  8 MB

  hipMemsetAsync(yk,   0, (size_t)B_SZ * DENC * 4, stream);
  hipMemsetAsync(ykbf, 0, (size_t)B_SZ * DENC * 2, stream);
  pack_H_kernel<<<dim3(DENC / 32, DIN / 32), dim3(32, 8), 0, stream>>>(H, Hbf, Htbf);

  double t = 1.0;
  for (int it = 0; it < T_ITERS; ++it) {
    // r = x - yk @ H^T : M=2048 N=1024 K=4096
    gemm_bt<64, DENC, 0><<<dim3(DIN / 64, B_SZ / 128), 256, 0, stream>>>(
        ykbf, Hbf, x, nullptr, nullptr, rbf, 0.f, 0, DIN);
    double tn = (1.0 + sqrt(1.0 + 4.0 * t * t)) * 0.5;
    float c = (float)((t - 1.0) / tn);
    int last = (it == T_ITERS - 1) ? 1 : 0;
    // g = r @ H ; fused FISTA update : M=2048 N=4096 K=1024
    gemm_bt<128, DIN, 1><<<dim3(DENC / 128, B_SZ / 128), 256, 0, stream>>>(
        rbf, Htbf, nullptr, yk, xold, ykbf, c, last, DENC);
    t = tn;
  }
  // z = x_new @ H^T : M=2048 N=1024 K=4096 (ykbf holds bf16(x_new) after last iter)
  gemm_bt<64, DENC, 2><<<dim3(DIN / 64, B_SZ / 128), 256, 0, stream>>>(
      ykbf, Hbf, nullptr, z_out, nullptr, nullptr, 0.f, 0, DIN);
}